// Round 6
// baseline (996.609 us; speedup 1.0000x reference)
//
#include <hip/hip_runtime.h>
#include <stdint.h>

#define DIMD 4096   // feature width (and K)
#define DIMB 4096   // batch
#define NLAYER 4
#define NT2 128     // K-tiles of BK=32

typedef unsigned short u16;
typedef __attribute__((ext_vector_type(4))) float f32x4;
typedef __attribute__((ext_vector_type(8))) __bf16 bf16x8;

__device__ __forceinline__ u16 f2bf(float f) {
    union { float f; uint32_t u; } v; v.f = f;
    return (u16)((v.u + 0x7fffu + ((v.u >> 16) & 1u)) >> 16);  // RNE
}

// ---------------- fp32 -> bf16 elementwise (x input) ----------------
__global__ void k_cvt(const float* __restrict__ in, u16* __restrict__ out) {
    int i = (blockIdx.x * 256 + threadIdx.x) * 4;
    float4 v = *reinterpret_cast<const float4*>(in + i);
    ushort4 r;
    r.x = f2bf(v.x); r.y = f2bf(v.y); r.z = f2bf(v.z); r.w = f2bf(v.w);
    *reinterpret_cast<ushort4*>(out + i) = r;
}

// ------- W[l][k][n] fp32 -> Wt4[l][n][k] bf16, all 4 layers in one launch -------
__global__ void k_trans(const float* __restrict__ W, u16* __restrict__ Wt) {
    __shared__ float tile[64][65];
    const int t = threadIdx.x;
    const size_t loff = (size_t)blockIdx.z * DIMD * DIMD;
    const int n0 = blockIdx.x * 64, k0 = blockIdx.y * 64;
    const int kr = t >> 4, c4 = (t & 15) * 4;
    #pragma unroll
    for (int r = 0; r < 4; ++r) {
        float4 v = *reinterpret_cast<const float4*>(W + loff + (size_t)(k0 + kr + r * 16) * DIMD + n0 + c4);
        tile[kr + r * 16][c4 + 0] = v.x;
        tile[kr + r * 16][c4 + 1] = v.y;
        tile[kr + r * 16][c4 + 2] = v.z;
        tile[kr + r * 16][c4 + 3] = v.w;
    }
    __syncthreads();
    const int nr = t >> 4, k4 = (t & 15) * 4;
    #pragma unroll
    for (int r = 0; r < 4; ++r) {
        int n = nr + r * 16;
        ushort4 o;
        o.x = f2bf(tile[k4 + 0][n]);
        o.y = f2bf(tile[k4 + 1][n]);
        o.z = f2bf(tile[k4 + 2][n]);
        o.w = f2bf(tile[k4 + 3][n]);
        *reinterpret_cast<ushort4*>(Wt + loff + (size_t)(n0 + n) * DIMD + k0 + k4) = o;
    }
}

// -------- 256x256 quad-buffered bf16 MFMA GEMM (BK=32, 1 barrier/tile) --------
// 512 threads = 8 waves (2M x 4N), per-wave 128x64 = 8x4 frags of 16x16x32.
// LDS: 4 buffers x (A 16K + B 16K) = 128 KiB. Swizzle chunk' = chunk^((row>>1)&3)
// (proven conflict-free, r1) via pre-swizzled global source; LDS linear.
// Tile t: stage(t+3) into buf (t+3)&3 at TOP (its last readers drained before
// bar(t) via the end-of-tile lgkmcnt(0)); 12 ds_reads + 32 MFMA with compiler
// counted-lgkm interleave — NO mid-tile barrier; end: lgkm(0), counted vmcnt
// (8 steady / 4 / 0 tail), s_barrier. Reads(t+1) safe: stage(t+1) is the
// oldest 4 of 12 outstanding GLDs, drained by vmcnt(8).
#define GLD(g, l) __builtin_amdgcn_global_load_lds( \
    (__attribute__((address_space(1))) void*)(g),   \
    (__attribute__((address_space(3))) void*)(l), 16, 0, 0)

__global__ __launch_bounds__(512, 2) void k_gemm(
        const u16* __restrict__ A, const u16* __restrict__ Bt,
        const float* __restrict__ bias, float* __restrict__ C,
        float* __restrict__ csum, float* __restrict__ csum2) {
    __shared__ __attribute__((aligned(16))) u16 As[4 * 8192];   // 64 KiB
    __shared__ __attribute__((aligned(16))) u16 Bs[4 * 8192];   // 64 KiB
    const int tid = threadIdx.x;
    const int lane = tid & 63, wv = tid >> 6;
    const int wm = wv >> 2, wn = wv & 3;          // 2 x 4 wave grid
    const int bm = blockIdx.y, bn = blockIdx.x;
    const int lr = lane & 15, lk = lane >> 4;

    // staging: per GLD, 512 threads x 16B = 128 rows x 32 cols (4 chunks/row)
    const int r0 = tid >> 2;                       // 0..127
    const int cswz = (tid & 3) ^ ((r0 >> 1) & 3);  // inverse-swizzled 16B chunk
    const u16* gA = A  + (size_t)(bm * 256 + r0) * DIMD + cswz * 8;
    const u16* gB = Bt + (size_t)(bn * 256 + r0) * DIMD + cswz * 8;

    // one stage = one matrix tile (256 rows x 32 cols = 16 KiB = 2 GLDs)
#define STG_A(t) do { \
    const u16* _s = gA + (size_t)(t) * 32; \
    u16* _d = As + (((t) & 3) * 8192) + wv * 512; \
    GLD(_s, _d); GLD(_s + (size_t)128 * DIMD, _d + 4096); \
} while (0)
#define STG_B(t) do { \
    const u16* _s = gB + (size_t)(t) * 32; \
    u16* _d = Bs + (((t) & 3) * 8192) + wv * 512; \
    GLD(_s, _d); GLD(_s + (size_t)128 * DIMD, _d + 4096); \
} while (0)

    // ds_read fragment offsets (u16 units), swizzled — r1-proven conflict-free
    int aoff[8], boff[4];
    #pragma unroll
    for (int mf = 0; mf < 8; ++mf) {
        int row = wm * 128 + mf * 16 + lr;
        aoff[mf] = row * 32 + ((lk ^ ((row >> 1) & 3)) << 3);
    }
    #pragma unroll
    for (int nf = 0; nf < 4; ++nf) {
        int row = wn * 64 + nf * 16 + lr;
        boff[nf] = row * 32 + ((lk ^ ((row >> 1) & 3)) << 3);
    }

    f32x4 acc[8][4] = {};
    bf16x8 a[8], b[4];

    // prologue: stage tiles 0,1,2 (12 GLDs); drain tile 0 only
    STG_A(0); STG_B(0); STG_A(1); STG_B(1); STG_A(2); STG_B(2);
    asm volatile("s_waitcnt vmcnt(8)" ::: "memory");
    __builtin_amdgcn_s_barrier();

    for (int t = 0; t < NT2; ++t) {
        const u16* Ab = As + (t & 3) * 8192;
        const u16* Bb = Bs + (t & 3) * 8192;

        // stage tile t+3 into buf (t+3)&3 (= (t-1)&3: readers drained pre-bar(t))
        if (t + 3 < NT2) { STG_A(t + 3); STG_B(t + 3); }

        // 12 ds_reads (B first: first MFMAs need b[.] + a[0])
        #pragma unroll
        for (int nf = 0; nf < 4; ++nf)
            b[nf] = *reinterpret_cast<const bf16x8*>(Bb + boff[nf]);
        #pragma unroll
        for (int mf = 0; mf < 8; ++mf)
            a[mf] = *reinterpret_cast<const bf16x8*>(Ab + aoff[mf]);

        // 32 MFMA, compiler-managed counted lgkm waits (no block sync here)
        __builtin_amdgcn_s_setprio(1);
        #pragma unroll
        for (int mf = 0; mf < 8; ++mf)
            #pragma unroll
            for (int nf = 0; nf < 4; ++nf)
                acc[mf][nf] = __builtin_amdgcn_mfma_f32_16x16x32_bf16(
                    a[mf], b[nf], acc[mf][nf], 0, 0, 0);
        __builtin_amdgcn_s_setprio(0);

        // all of this wave's reads drained (free: MFMAs consumed them) so the
        // next tile's top-staging into buf (t&3... t+4) is WAR-safe post-bar
        asm volatile("s_waitcnt lgkmcnt(0)" ::: "memory");
        __builtin_amdgcn_sched_barrier(0);
        if (t + 3 < NT2)      asm volatile("s_waitcnt vmcnt(8)" ::: "memory");
        else if (t + 2 < NT2) asm volatile("s_waitcnt vmcnt(4)" ::: "memory");
        else                  asm volatile("s_waitcnt vmcnt(0)" ::: "memory");
        __builtin_amdgcn_s_barrier();
    }

    // epilogue: bias, fp32 C, BN stats (C/D: col = lane&15, row = lk*4 + reg)
    #pragma unroll
    for (int nf = 0; nf < 4; ++nf) {
        int col = bn * 256 + wn * 64 + nf * 16 + lr;
        float bv = bias[col];
        float s1 = 0.f, s2 = 0.f;
        #pragma unroll
        for (int mf = 0; mf < 8; ++mf) {
            int rbase = bm * 256 + wm * 128 + mf * 16 + lk * 4;
            #pragma unroll
            for (int r = 0; r < 4; ++r) {
                float v = acc[mf][nf][r] + bv;
                C[(size_t)(rbase + r) * DIMD + col] = v;
                s1 += v; s2 += v * v;
            }
        }
        s1 += __shfl_xor(s1, 16); s1 += __shfl_xor(s1, 32);
        s2 += __shfl_xor(s2, 16); s2 += __shfl_xor(s2, 32);
        if (lk == 0) {
            atomicAdd(&csum[col], s1);
            atomicAdd(&csum2[col], s2);
        }
    }
#undef STG_A
#undef STG_B
}

// ------- normalize + relu -> bf16 (layers 0..2); BN finalize fused; float4 -------
__global__ void k_norm(const float* __restrict__ H, const float* __restrict__ sum,
                       const float* __restrict__ sum2, const float* __restrict__ gamma,
                       const float* __restrict__ beta, u16* __restrict__ o) {
    int j = (blockIdx.x * 256 + threadIdx.x) * 4;
    int i0 = blockIdx.y * 128;
    float4 sm = *reinterpret_cast<const float4*>(sum + j);
    float4 s2 = *reinterpret_cast<const float4*>(sum2 + j);
    float4 gm = *reinterpret_cast<const float4*>(gamma + j);
    float4 bt = *reinterpret_cast<const float4*>(beta + j);
    float s[4], tt[4];
    #pragma unroll
    for (int c = 0; c < 4; ++c) {
        float mu = (&sm.x)[c] * (1.0f / DIMB);
        float var = (&s2.x)[c] * (1.0f / DIMB) - mu * mu;
        s[c] = (&gm.x)[c] * rsqrtf(var + 1e-5f);
        tt[c] = (&bt.x)[c] - mu * s[c];
    }
    for (int i = i0; i < i0 + 128; ++i) {
        float4 h = *reinterpret_cast<const float4*>(H + (size_t)i * DIMD + j);
        ushort4 r;
        #pragma unroll
        for (int c = 0; c < 4; ++c)
            (&r.x)[c] = f2bf(fmaxf((&h.x)[c] * s[c] + tt[c], 0.0f));
        *reinterpret_cast<ushort4*>(o + (size_t)i * DIMD + j) = r;
    }
}

// ------- layer 3: normalize + relu + exp in place, column exp-sums; float4 -------
__global__ void k_normexp(float* __restrict__ H, const float* __restrict__ sum,
                          const float* __restrict__ sum2, const float* __restrict__ gamma,
                          const float* __restrict__ beta, float* __restrict__ esum) {
    int j = (blockIdx.x * 256 + threadIdx.x) * 4;
    int i0 = blockIdx.y * 128;
    float4 sm = *reinterpret_cast<const float4*>(sum + j);
    float4 s2 = *reinterpret_cast<const float4*>(sum2 + j);
    float4 gm = *reinterpret_cast<const float4*>(gamma + j);
    float4 bt = *reinterpret_cast<const float4*>(beta + j);
    float s[4], tt[4], acc[4] = {0.f, 0.f, 0.f, 0.f};
    #pragma unroll
    for (int c = 0; c < 4; ++c) {
        float mu = (&sm.x)[c] * (1.0f / DIMB);
        float var = (&s2.x)[c] * (1.0f / DIMB) - mu * mu;
        s[c] = (&gm.x)[c] * rsqrtf(var + 1e-5f);
        tt[c] = (&bt.x)[c] - mu * s[c];
    }
    for (int i = i0; i < i0 + 128; ++i) {
        float4 h = *reinterpret_cast<const float4*>(H + (size_t)i * DIMD + j);
        #pragma unroll
        for (int c = 0; c < 4; ++c) {
            float e = __expf(fmaxf((&h.x)[c] * s[c] + tt[c], 0.0f));
            (&h.x)[c] = e;
            acc[c] += e;
        }
        *reinterpret_cast<float4*>(H + (size_t)i * DIMD + j) = h;
    }
    #pragma unroll
    for (int c = 0; c < 4; ++c) atomicAdd(&esum[j + c], acc[c]);
}

// ---------------- softmax divide, in place ----------------
__global__ void k_div(float* __restrict__ H, const float* __restrict__ esum) {
    int i = (blockIdx.x * 256 + threadIdx.x) * 4;
    float4 v = *reinterpret_cast<const float4*>(H + i);
    const float4 e = *reinterpret_cast<const float4*>(esum + (i & (DIMD - 1)));
    v.x /= e.x; v.y /= e.y; v.z /= e.z; v.w /= e.w;
    *reinterpret_cast<float4*>(H + i) = v;
}

extern "C" void kernel_launch(void* const* d_in, const int* in_sizes, int n_in,
                              void* d_out, int out_size, void* d_ws, size_t ws_size,
                              hipStream_t stream) {
    (void)in_sizes; (void)n_in; (void)out_size; (void)ws_size;
    const float* x     = (const float*)d_in[0];
    const float* W     = (const float*)d_in[1];
    const float* b     = (const float*)d_in[2];
    const float* gamma = (const float*)d_in[3];
    const float* beta  = (const float*)d_in[4];
    float* out = (float*)d_out;                       // doubles as H scratch (fp32 4096x4096)

    char* ws = (char*)d_ws;                               // ws >= 1 GiB (observed)
    u16*  Abf = (u16*)ws;                                 // 32 MiB activation bf16
    u16*  Wt4 = (u16*)(ws + (size_t)32 * 1024 * 1024);    // 4 x 32 MiB transposed weights
    float* stats = (float*)(ws + (size_t)160 * 1024 * 1024);
    // stats: per layer l: sum = stats + l*8192, sum2 = sum + 4096; esum = stats + 32768
    hipMemsetAsync(stats, 0, (4 * 8192 + 4096) * sizeof(float), stream);

    k_cvt<<<DIMB * DIMD / 1024, 256, 0, stream>>>(x, Abf);
    k_trans<<<dim3(64, 64, 4), 256, 0, stream>>>(W, Wt4);

    for (int l = 0; l < NLAYER; ++l) {
        float* sum = stats + l * 8192;
        float* sum2 = sum + 4096;
        k_gemm<<<dim3(16, 16), 512, 0, stream>>>(Abf, Wt4 + (size_t)l * DIMD * DIMD,
                                                 b + l * DIMD, out, sum, sum2);
        if (l < NLAYER - 1)
            k_norm<<<dim3(4, 32), 256, 0, stream>>>(out, sum, sum2,
                gamma + l * DIMD, beta + l * DIMD, Abf);
        else
            k_normexp<<<dim3(4, 32), 256, 0, stream>>>(out, sum, sum2,
                gamma + l * DIMD, beta + l * DIMD, stats + 32768);
    }
    k_div<<<DIMB * DIMD / 1024, 256, 0, stream>>>(out, stats + 32768);
}

// Round 7
// 731.059 us; speedup vs baseline: 1.3632x; 1.3632x over previous
//
#include <hip/hip_runtime.h>
#include <stdint.h>

#define DIMD 4096   // feature width (and K)
#define DIMB 4096   // batch
#define NLAYER 4
#define NT (DIMD / 64)   // 64 K-tiles of BK=64

typedef unsigned short u16;
typedef __attribute__((ext_vector_type(4))) float f32x4;
typedef __attribute__((ext_vector_type(8))) __bf16 bf16x8;

__device__ __forceinline__ u16 f2bf(float f) {
    union { float f; uint32_t u; } v; v.f = f;
    return (u16)((v.u + 0x7fffu + ((v.u >> 16) & 1u)) >> 16);  // RNE
}
__device__ __forceinline__ float bf2f(u16 u) {
    union { uint32_t u; float f; } v; v.u = ((uint32_t)u) << 16;
    return v.f;
}

// ---------------- fp32 -> bf16 elementwise (x input) ----------------
__global__ void k_cvt(const float* __restrict__ in, u16* __restrict__ out) {
    int i = (blockIdx.x * 256 + threadIdx.x) * 4;
    float4 v = *reinterpret_cast<const float4*>(in + i);
    ushort4 r;
    r.x = f2bf(v.x); r.y = f2bf(v.y); r.z = f2bf(v.z); r.w = f2bf(v.w);
    *reinterpret_cast<ushort4*>(out + i) = r;
}

// ------- W[l][k][n] fp32 -> Wt4[l][n][k] bf16, all 4 layers in one launch -------
__global__ void k_trans(const float* __restrict__ W, u16* __restrict__ Wt) {
    __shared__ float tile[64][65];
    const int t = threadIdx.x;
    const size_t loff = (size_t)blockIdx.z * DIMD * DIMD;
    const int n0 = blockIdx.x * 64, k0 = blockIdx.y * 64;
    const int kr = t >> 4, c4 = (t & 15) * 4;
    #pragma unroll
    for (int r = 0; r < 4; ++r) {
        float4 v = *reinterpret_cast<const float4*>(W + loff + (size_t)(k0 + kr + r * 16) * DIMD + n0 + c4);
        tile[kr + r * 16][c4 + 0] = v.x;
        tile[kr + r * 16][c4 + 1] = v.y;
        tile[kr + r * 16][c4 + 2] = v.z;
        tile[kr + r * 16][c4 + 3] = v.w;
    }
    __syncthreads();
    const int nr = t >> 4, k4 = (t & 15) * 4;
    #pragma unroll
    for (int r = 0; r < 4; ++r) {
        int n = nr + r * 16;
        ushort4 o;
        o.x = f2bf(tile[k4 + 0][n]);
        o.y = f2bf(tile[k4 + 1][n]);
        o.z = f2bf(tile[k4 + 2][n]);
        o.w = f2bf(tile[k4 + 3][n]);
        *reinterpret_cast<ushort4*>(Wt + loff + (size_t)(n0 + n) * DIMD + k0 + k4) = o;
    }
}

// ---------------- 256x256 8-phase bf16 MFMA GEMM (r3 structure) ----------------
// BM=BN=256, BK=64, 512 threads = 8 waves (2M x 4N), per-wave 128x64 as 8x4
// frags of 16x16x32. LDS dbuf 128 KiB; XOR chunk swizzle (chunk^(row&7), 16B)
// on pre-swizzled global source + ds_read addr (measured conflict-free).
// 4 phases/tile, each {ds_reads | stage | barrier | lgkm0 | setprio+16 MFMA |
// barrier}; stage t+2's B at P3, A at P4; ONE counted vmcnt(8)/tile.
// + bijective XCD swizzle on block id; + bf16 C-write (H), stats from fp32.
#define GLD(g, l) __builtin_amdgcn_global_load_lds( \
    (__attribute__((address_space(1))) void*)(g),   \
    (__attribute__((address_space(3))) void*)(l), 16, 0, 0)

__global__ __launch_bounds__(512, 2) void k_gemm(
        const u16* __restrict__ A, const u16* __restrict__ Bt,
        const float* __restrict__ bias, u16* __restrict__ H,
        float* __restrict__ csum, float* __restrict__ csum2) {
    __shared__ __attribute__((aligned(16))) u16 As[2 * 256 * 64];   // 64 KiB
    __shared__ __attribute__((aligned(16))) u16 Bs[2 * 256 * 64];   // 64 KiB
    const int tid = threadIdx.x;
    const int lane = tid & 63, wv = tid >> 6;
    const int wm = wv >> 2, wn = wv & 3;          // 2 x 4 wave grid
    // XCD-aware bijective swizzle: 256 blocks, 8 XCDs, 32 contiguous per XCD
    const int bid = blockIdx.y * 16 + blockIdx.x;
    const int swz = (bid & 7) * 32 + (bid >> 3);
    const int bm = swz >> 4, bn = swz & 15;
    const int lr = lane & 15, lk = lane >> 4;

    // staging geometry: per GLD issue, 512 threads x 16B cover 64 rows x 64 cols
    const int r0 = tid >> 3;                       // 0..63
    const int cswz = (tid & 7) ^ (r0 & 7);         // inverse-swizzled 16B chunk
    const u16* gA = A  + (size_t)(bm * 256 + r0) * DIMD + cswz * 8;
    const u16* gB = Bt + (size_t)(bn * 256 + r0) * DIMD + cswz * 8;

    // unit = one matrix half (128 rows x 64 cols = 16 KiB = 2 GLD issues)
#define STAGE_A(h, t, buf) do { \
    const u16* _s = gA + (size_t)(h) * 128 * DIMD + (size_t)(t) * 64; \
    u16* _d = As + (buf) * 16384 + (h) * 8192 + wv * 512; \
    GLD(_s, _d); GLD(_s + (size_t)64 * DIMD, _d + 4096); \
} while (0)
#define STAGE_B(h, t, buf) do { \
    const u16* _s = gB + (size_t)(h) * 128 * DIMD + (size_t)(t) * 64; \
    u16* _d = Bs + (buf) * 16384 + (h) * 8192 + wv * 512; \
    GLD(_s, _d); GLD(_s + (size_t)64 * DIMD, _d + 4096); \
} while (0)

    // ds_read fragment offsets (u16 units), swizzled — measured conflict-free
    int aoff[4][2], boff[2][2];
    #pragma unroll
    for (int mf = 0; mf < 4; ++mf)
        #pragma unroll
        for (int ks = 0; ks < 2; ++ks) {
            int row = wm * 128 + mf * 16 + lr;
            aoff[mf][ks] = row * 64 + ((ks * 4 + lk) ^ (row & 7)) * 8;
        }
    #pragma unroll
    for (int nf = 0; nf < 2; ++nf)
        #pragma unroll
        for (int ks = 0; ks < 2; ++ks) {
            int row = wn * 64 + nf * 16 + lr;
            boff[nf][ks] = row * 64 + ((ks * 4 + lk) ^ (row & 7)) * 8;
        }

    f32x4 acc[8][4] = {};          // [mh*4+mf][nh*2+nf]
    bf16x8 a[4][2], b0[2][2], b1[2][2];

    // prologue: tiles 0 and 1 fully issued; drain tile 0, keep tile 1 in flight
    STAGE_B(0, 0, 0); STAGE_B(1, 0, 0); STAGE_A(0, 0, 0); STAGE_A(1, 0, 0);
    STAGE_B(0, 1, 1); STAGE_B(1, 1, 1); STAGE_A(0, 1, 1); STAGE_A(1, 1, 1);
    asm volatile("s_waitcnt vmcnt(8)" ::: "memory");
    __builtin_amdgcn_s_barrier();

    for (int t = 0; t < NT; ++t) {
        const int cur = t & 1;
        const u16* Ab = As + cur * 16384;
        const u16* Bb = Bs + cur * 16384;
        const bool pf = (t + 2 < NT);

        // ===== P1: read A[q0] + B[first 32 cols]; MFMA q(0,0)
        #pragma unroll
        for (int mf = 0; mf < 4; ++mf)
            #pragma unroll
            for (int ks = 0; ks < 2; ++ks)
                a[mf][ks] = *reinterpret_cast<const bf16x8*>(Ab + aoff[mf][ks]);
        #pragma unroll
        for (int nf = 0; nf < 2; ++nf)
            #pragma unroll
            for (int ks = 0; ks < 2; ++ks)
                b0[nf][ks] = *reinterpret_cast<const bf16x8*>(Bb + boff[nf][ks]);
        __builtin_amdgcn_s_barrier();
        asm volatile("s_waitcnt lgkmcnt(0)" ::: "memory");
        __builtin_amdgcn_s_setprio(1);
        #pragma unroll
        for (int mf = 0; mf < 4; ++mf)
            #pragma unroll
            for (int nf = 0; nf < 2; ++nf)
                #pragma unroll
                for (int ks = 0; ks < 2; ++ks)
                    acc[mf][nf] = __builtin_amdgcn_mfma_f32_16x16x32_bf16(
                        a[mf][ks], b0[nf][ks], acc[mf][nf], 0, 0, 0);
        __builtin_amdgcn_s_setprio(0);
        __builtin_amdgcn_s_barrier();

        // ===== P2: read B[second 32 cols]; MFMA q(0,1)
        #pragma unroll
        for (int nf = 0; nf < 2; ++nf)
            #pragma unroll
            for (int ks = 0; ks < 2; ++ks)
                b1[nf][ks] = *reinterpret_cast<const bf16x8*>(Bb + 2048 + boff[nf][ks]);
        __builtin_amdgcn_s_barrier();
        asm volatile("s_waitcnt lgkmcnt(0)" ::: "memory");
        __builtin_amdgcn_s_setprio(1);
        #pragma unroll
        for (int mf = 0; mf < 4; ++mf)
            #pragma unroll
            for (int nf = 0; nf < 2; ++nf)
                #pragma unroll
                for (int ks = 0; ks < 2; ++ks)
                    acc[mf][2 + nf] = __builtin_amdgcn_mfma_f32_16x16x32_bf16(
                        a[mf][ks], b1[nf][ks], acc[mf][2 + nf], 0, 0, 0);
        __builtin_amdgcn_s_setprio(0);
        __builtin_amdgcn_s_barrier();

        // ===== P3: read A[q1]; stage B(t+2) into cur (B reads done at P2); MFMA q(1,1)
        #pragma unroll
        for (int mf = 0; mf < 4; ++mf)
            #pragma unroll
            for (int ks = 0; ks < 2; ++ks)
                a[mf][ks] = *reinterpret_cast<const bf16x8*>(Ab + 4096 + aoff[mf][ks]);
        if (pf) { STAGE_B(0, t + 2, cur); STAGE_B(1, t + 2, cur); }
        __builtin_amdgcn_s_barrier();
        asm volatile("s_waitcnt lgkmcnt(0)" ::: "memory");
        __builtin_amdgcn_s_setprio(1);
        #pragma unroll
        for (int mf = 0; mf < 4; ++mf)
            #pragma unroll
            for (int nf = 0; nf < 2; ++nf)
                #pragma unroll
                for (int ks = 0; ks < 2; ++ks)
                    acc[4 + mf][2 + nf] = __builtin_amdgcn_mfma_f32_16x16x32_bf16(
                        a[mf][ks], b1[nf][ks], acc[4 + mf][2 + nf], 0, 0, 0);
        __builtin_amdgcn_s_setprio(0);
        __builtin_amdgcn_s_barrier();

        // ===== P4: stage A(t+2) into cur (A reads done at P3); MFMA q(1,0);
        //           counted vmcnt; tile-end barrier
        if (pf) { STAGE_A(0, t + 2, cur); STAGE_A(1, t + 2, cur); }
        __builtin_amdgcn_s_setprio(1);
        #pragma unroll
        for (int mf = 0; mf < 4; ++mf)
            #pragma unroll
            for (int nf = 0; nf < 2; ++nf)
                #pragma unroll
                for (int ks = 0; ks < 2; ++ks)
                    acc[4 + mf][nf] = __builtin_amdgcn_mfma_f32_16x16x32_bf16(
                        a[mf][ks], b0[nf][ks], acc[4 + mf][nf], 0, 0, 0);
        __builtin_amdgcn_s_setprio(0);
        if (pf) asm volatile("s_waitcnt vmcnt(8)" ::: "memory");
        else    asm volatile("s_waitcnt vmcnt(0)" ::: "memory");
        __builtin_amdgcn_s_barrier();
    }

    // epilogue: bias, bf16 H-write, BN stats from exact fp32
    #pragma unroll
    for (int nh = 0; nh < 2; ++nh)
        #pragma unroll
        for (int nf = 0; nf < 2; ++nf) {
            int n = nh * 2 + nf;
            int col = bn * 256 + wn * 64 + nh * 32 + nf * 16 + lr;
            float bv = bias[col];
            float s1 = 0.f, s2 = 0.f;
            #pragma unroll
            for (int m = 0; m < 8; ++m) {
                int rbase = bm * 256 + wm * 128 + (m >> 2) * 64 + (m & 3) * 16 + lk * 4;
                #pragma unroll
                for (int r = 0; r < 4; ++r) {
                    float v = acc[m][n][r] + bv;
                    H[(size_t)(rbase + r) * DIMD + col] = f2bf(v);
                    s1 += v; s2 += v * v;
                }
            }
            s1 += __shfl_xor(s1, 16); s1 += __shfl_xor(s1, 32);
            s2 += __shfl_xor(s2, 16); s2 += __shfl_xor(s2, 32);
            if (lk == 0) {
                atomicAdd(&csum[col], s1);
                atomicAdd(&csum2[col], s2);
            }
        }
#undef STAGE_A
#undef STAGE_B
}

// ------- normalize + relu -> bf16 (layers 0..2); BN finalize fused -------
__global__ void k_norm(const u16* __restrict__ H, const float* __restrict__ sum,
                       const float* __restrict__ sum2, const float* __restrict__ gamma,
                       const float* __restrict__ beta, u16* __restrict__ o) {
    int j = (blockIdx.x * 256 + threadIdx.x) * 4;
    int i0 = blockIdx.y * 32;
    float4 sm = *reinterpret_cast<const float4*>(sum + j);
    float4 s2 = *reinterpret_cast<const float4*>(sum2 + j);
    float4 gm = *reinterpret_cast<const float4*>(gamma + j);
    float4 bt = *reinterpret_cast<const float4*>(beta + j);
    float s[4], tt[4];
    #pragma unroll
    for (int c = 0; c < 4; ++c) {
        float mu = (&sm.x)[c] * (1.0f / DIMB);
        float var = (&s2.x)[c] * (1.0f / DIMB) - mu * mu;
        s[c] = (&gm.x)[c] * rsqrtf(var + 1e-5f);
        tt[c] = (&bt.x)[c] - mu * s[c];
    }
    for (int i = i0; i < i0 + 32; ++i) {
        ushort4 h = *reinterpret_cast<const ushort4*>(H + (size_t)i * DIMD + j);
        ushort4 r;
        #pragma unroll
        for (int c = 0; c < 4; ++c)
            (&r.x)[c] = f2bf(fmaxf(bf2f((&h.x)[c]) * s[c] + tt[c], 0.0f));
        *reinterpret_cast<ushort4*>(o + (size_t)i * DIMD + j) = r;
    }
}

// ------- layer 3 pass A: column sums of exp(relu(norm(h))) -------
__global__ void k_esum(const u16* __restrict__ H, const float* __restrict__ sum,
                       const float* __restrict__ sum2, const float* __restrict__ gamma,
                       const float* __restrict__ beta, float* __restrict__ esum) {
    int j = (blockIdx.x * 256 + threadIdx.x) * 4;
    int i0 = blockIdx.y * 32;
    float4 sm = *reinterpret_cast<const float4*>(sum + j);
    float4 s2 = *reinterpret_cast<const float4*>(sum2 + j);
    float4 gm = *reinterpret_cast<const float4*>(gamma + j);
    float4 bt = *reinterpret_cast<const float4*>(beta + j);
    float s[4], tt[4], acc[4] = {0.f, 0.f, 0.f, 0.f};
    #pragma unroll
    for (int c = 0; c < 4; ++c) {
        float mu = (&sm.x)[c] * (1.0f / DIMB);
        float var = (&s2.x)[c] * (1.0f / DIMB) - mu * mu;
        s[c] = (&gm.x)[c] * rsqrtf(var + 1e-5f);
        tt[c] = (&bt.x)[c] - mu * s[c];
    }
    for (int i = i0; i < i0 + 32; ++i) {
        ushort4 h = *reinterpret_cast<const ushort4*>(H + (size_t)i * DIMD + j);
        #pragma unroll
        for (int c = 0; c < 4; ++c)
            acc[c] += __expf(fmaxf(bf2f((&h.x)[c]) * s[c] + tt[c], 0.0f));
    }
    #pragma unroll
    for (int c = 0; c < 4; ++c) atomicAdd(&esum[j + c], acc[c]);
}

// ------- layer 3 pass B: recompute exp (bit-identical), divide, write fp32 -------
__global__ void k_final(const u16* __restrict__ H, const float* __restrict__ sum,
                        const float* __restrict__ sum2, const float* __restrict__ gamma,
                        const float* __restrict__ beta, const float* __restrict__ esum,
                        float* __restrict__ out) {
    int j = (blockIdx.x * 256 + threadIdx.x) * 4;
    int i0 = blockIdx.y * 32;
    float4 sm = *reinterpret_cast<const float4*>(sum + j);
    float4 s2 = *reinterpret_cast<const float4*>(sum2 + j);
    float4 gm = *reinterpret_cast<const float4*>(gamma + j);
    float4 bt = *reinterpret_cast<const float4*>(beta + j);
    float4 es = *reinterpret_cast<const float4*>(esum + j);
    float s[4], tt[4], inv[4];
    #pragma unroll
    for (int c = 0; c < 4; ++c) {
        float mu = (&sm.x)[c] * (1.0f / DIMB);
        float var = (&s2.x)[c] * (1.0f / DIMB) - mu * mu;
        s[c] = (&gm.x)[c] * rsqrtf(var + 1e-5f);
        tt[c] = (&bt.x)[c] - mu * s[c];
        inv[c] = 1.0f / (&es.x)[c];
    }
    for (int i = i0; i < i0 + 32; ++i) {
        ushort4 h = *reinterpret_cast<const ushort4*>(H + (size_t)i * DIMD + j);
        float4 o;
        #pragma unroll
        for (int c = 0; c < 4; ++c)
            (&o.x)[c] = __expf(fmaxf(bf2f((&h.x)[c]) * s[c] + tt[c], 0.0f)) * inv[c];
        *reinterpret_cast<float4*>(out + (size_t)i * DIMD + j) = o;
    }
}

extern "C" void kernel_launch(void* const* d_in, const int* in_sizes, int n_in,
                              void* d_out, int out_size, void* d_ws, size_t ws_size,
                              hipStream_t stream) {
    (void)in_sizes; (void)n_in; (void)out_size; (void)ws_size;
    const float* x     = (const float*)d_in[0];
    const float* W     = (const float*)d_in[1];
    const float* b     = (const float*)d_in[2];
    const float* gamma = (const float*)d_in[3];
    const float* beta  = (const float*)d_in[4];
    float* out = (float*)d_out;

    char* ws = (char*)d_ws;                               // ws = 1 GiB
    u16*  Abf = (u16*)ws;                                 // 32 MiB activation bf16
    u16*  Wt4 = (u16*)(ws + (size_t)32 * 1024 * 1024);    // 4 x 32 MiB transposed weights
    u16*  Hbf = (u16*)(ws + (size_t)160 * 1024 * 1024);   // 32 MiB hidden bf16
    float* stats = (float*)(ws + (size_t)192 * 1024 * 1024);
    // stats: per layer l: sum = stats + l*8192, sum2 = sum + 4096; esum = stats + 32768
    hipMemsetAsync(stats, 0, (4 * 8192 + 4096) * sizeof(float), stream);

    k_cvt<<<DIMB * DIMD / 1024, 256, 0, stream>>>(x, Abf);
    k_trans<<<dim3(64, 64, 4), 256, 0, stream>>>(W, Wt4);

    for (int l = 0; l < NLAYER; ++l) {
        float* sum = stats + l * 8192;
        float* sum2 = sum + 4096;
        k_gemm<<<dim3(16, 16), 512, 0, stream>>>(Abf, Wt4 + (size_t)l * DIMD * DIMD,
                                                 b + l * DIMD, Hbf, sum, sum2);
        if (l < NLAYER - 1)
            k_norm<<<dim3(4, 128), 256, 0, stream>>>(Hbf, sum, sum2,
                gamma + l * DIMD, beta + l * DIMD, Abf);
        else
            k_esum<<<dim3(4, 128), 256, 0, stream>>>(Hbf, sum, sum2,
                gamma + l * DIMD, beta + l * DIMD, stats + 32768);
    }
    k_final<<<dim3(4, 128), 256, 0, stream>>>(Hbf, stats + 3 * 8192, stats + 3 * 8192 + 4096,
        gamma + 3 * DIMD, beta + 3 * DIMD, stats + 32768, out);
}